// Round 6
// baseline (592.385 us; speedup 1.0000x reference)
//
#include <hip/hip_runtime.h>
#include <math.h>

#define BD 8
#define CD 256
#define ND 4096
#define DA 64

typedef __attribute__((ext_vector_type(8))) short short8v;
typedef __attribute__((ext_vector_type(4))) float float4v;

static __device__ __forceinline__ float4v mfma16(short8v a, short8v b, float4v c) {
  return __builtin_amdgcn_mfma_f32_16x16x32_bf16(a, b, c, 0, 0, 0);
}
static __device__ __forceinline__ unsigned short f2bf(float f) {
  union { float f; unsigned int u; } v; v.f = f;
  return (unsigned short)((v.u + 0x7fffu + ((v.u >> 16) & 1u)) >> 16);
}
static __device__ __forceinline__ float bf2f(unsigned short h) {
  union { unsigned int u; float f; } v; v.u = (unsigned int)h << 16;
  return v.f;
}
// XOR-swizzled LDS offset (ushort units) for rows of 64 bf16 (8 x 16B chunks).
static __device__ __forceinline__ int sw(int row, int c8) {
  return row * 64 + (((c8) ^ (row & 7)) << 3);
}
typedef const __attribute__((address_space(1))) unsigned int g_u32;
typedef __attribute__((address_space(3))) unsigned int l_u32;
static __device__ __forceinline__ void gld16(const void* g, void* l) {
  __builtin_amdgcn_global_load_lds((g_u32*)g, (l_u32*)l, 16, 0, 0);
}

// ---------------------------------------------------------------------------
// k_prep: x [b][c][n] fp32 -> xTh/xTl [b][n][256] split bf16 (transposed).
// ---------------------------------------------------------------------------
__global__ __launch_bounds__(256) void k_prep(const float* __restrict__ x,
                                              unsigned short* __restrict__ xTh,
                                              unsigned short* __restrict__ xTl) {
  const int n0 = blockIdx.x * 64, c0 = blockIdx.y * 64, b = blockIdx.z;
  __shared__ float Xs[64][68];
  const int tid = threadIdx.x;
  const int r0 = tid >> 4, col4 = (tid & 15) * 4;
#pragma unroll
  for (int j = 0; j < 4; ++j) {
    int r = r0 + j * 16;
    *(float4*)&Xs[r][col4] =
        *(const float4*)&x[((size_t)(b * CD + c0 + r)) * ND + n0 + col4];
  }
  __syncthreads();
  const int n = tid >> 2, cg = (tid & 3) * 16;
  unsigned short h[16], l[16];
#pragma unroll
  for (int j = 0; j < 16; ++j) {
    float v = Xs[cg + j][n];
    h[j] = f2bf(v);
    l[j] = f2bf(v - bf2f(h[j]));
  }
  size_t o = ((size_t)b * ND + n0 + n) * CD + c0 + cg;
#pragma unroll
  for (int j = 0; j < 4; ++j) {
    *(ushort4*)&xTh[o + j * 4] = *(ushort4*)&h[j * 4];
    *(ushort4*)&xTl[o + j * 4] = *(ushort4*)&l[j * 4];
  }
}

// ---------------------------------------------------------------------------
// k_prepW: split weights fp32 -> bf16 hi/lo. Wch/Wcl = [Wq;Wk;Wv] rows 0..383.
// ---------------------------------------------------------------------------
__global__ void k_prepW(const float* __restrict__ Wq, const float* __restrict__ Wk,
                        const float* __restrict__ Wv, const float* __restrict__ Wp,
                        unsigned short* Wch, unsigned short* Wcl,
                        unsigned short* Wph, unsigned short* Wpl) {
  int i = blockIdx.x * 256 + threadIdx.x;  // 640 rows x 64 float4
  int row = i >> 6, c4 = (i & 63) * 4;
  const float* src; unsigned short *dh, *dl; int r, drow;
  if (row < 64)       { src = Wq; r = row;       dh = Wch; dl = Wcl; drow = row; }
  else if (row < 128) { src = Wk; r = row - 64;  dh = Wch; dl = Wcl; drow = row; }
  else if (row < 384) { src = Wv; r = row - 128; dh = Wch; dl = Wcl; drow = row; }
  else                { src = Wp; r = row - 384; dh = Wph; dl = Wpl; drow = row - 384; }
  float4 f = *(const float4*)&src[(size_t)r * 256 + c4];
  ushort4 hh, ll;
  hh.x = f2bf(f.x); hh.y = f2bf(f.y); hh.z = f2bf(f.z); hh.w = f2bf(f.w);
  ll.x = f2bf(f.x - bf2f(hh.x)); ll.y = f2bf(f.y - bf2f(hh.y));
  ll.z = f2bf(f.z - bf2f(hh.z)); ll.w = f2bf(f.w - bf2f(hh.w));
  *(ushort4*)&dh[(size_t)drow * 256 + c4] = hh;
  *(ushort4*)&dl[(size_t)drow * 256 + c4] = ll;
}

// ---------------------------------------------------------------------------
// k_proj: MERGED q/k/v projection (reads xT once, LDS k-slices, 3-product).
// grid (ND/128, B), 512 thr. q: hi only; k: hi+lo; v: transposed bf16.
// ---------------------------------------------------------------------------
__global__ __launch_bounds__(512) void k_proj(
    const unsigned short* __restrict__ xTh, const unsigned short* __restrict__ xTl,
    const unsigned short* __restrict__ Wch, const unsigned short* __restrict__ Wcl,
    unsigned short* __restrict__ qh, unsigned short* __restrict__ kh,
    unsigned short* __restrict__ kl, unsigned short* __restrict__ vT) {
  const int n0 = blockIdx.x * 128, b = blockIdx.y;
  const int tid = threadIdx.x, w = tid >> 6, lane = tid & 63, lq = lane & 15,
            quad = lane >> 4;
  __shared__ __align__(16) unsigned short xs[2][2][128][40];
  float4v O[24];
#pragma unroll
  for (int t = 0; t < 24; ++t) O[t] = (float4v){0.f, 0.f, 0.f, 0.f};

  const int srow = tid >> 2, sc4 = tid & 3;
  uint4 rh, rl;
  auto load_slice = [&](int ks) {
    size_t a = ((size_t)b * ND + n0 + srow) * CD + ks * 32 + sc4 * 8;
    rh = *(const uint4*)(xTh + a);
    rl = *(const uint4*)(xTl + a);
  };
  auto write_slice = [&](int buf) {
    *(uint4*)&xs[buf][0][srow][sc4 * 8] = rh;
    *(uint4*)&xs[buf][1][srow][sc4 * 8] = rl;
  };
  load_slice(0); write_slice(0);
#pragma unroll 1
  for (int ks = 0; ks < 8; ++ks) {
    __syncthreads();
    if (ks < 7) load_slice(ks + 1);
    short8v bxh = *(const short8v*)&xs[ks & 1][0][w * 16 + lq][quad * 8];
    short8v bxl = *(const short8v*)&xs[ks & 1][1][w * 16 + lq][quad * 8];
#pragma unroll
    for (int t = 0; t < 24; ++t) {
      size_t a = (size_t)(t * 16 + lq) * CD + ks * 32 + quad * 8;
      short8v awh = *(const short8v*)(Wch + a);
      short8v awl = *(const short8v*)(Wcl + a);
      O[t] = mfma16(awh, bxh, O[t]);
      O[t] = mfma16(awl, bxh, O[t]);
      O[t] = mfma16(awh, bxl, O[t]);
    }
    if (ks < 7) write_slice((ks + 1) & 1);
  }
  const int n = n0 + w * 16 + lq;
#pragma unroll
  for (int t = 0; t < 24; ++t) {
    if (t < 4) {
      ushort4 hh;
      hh.x = f2bf(O[t][0]); hh.y = f2bf(O[t][1]);
      hh.z = f2bf(O[t][2]); hh.w = f2bf(O[t][3]);
      *(ushort4*)&qh[((size_t)b * ND + n) * DA + t * 16 + quad * 4] = hh;
    } else if (t < 8) {
      ushort4 hh, ll;
      hh.x = f2bf(O[t][0]); hh.y = f2bf(O[t][1]);
      hh.z = f2bf(O[t][2]); hh.w = f2bf(O[t][3]);
      ll.x = f2bf(O[t][0] - bf2f(hh.x)); ll.y = f2bf(O[t][1] - bf2f(hh.y));
      ll.z = f2bf(O[t][2] - bf2f(hh.z)); ll.w = f2bf(O[t][3] - bf2f(hh.w));
      size_t o = ((size_t)b * ND + n) * DA + (t - 4) * 16 + quad * 4;
      *(ushort4*)&kh[o] = hh;
      *(ushort4*)&kl[o] = ll;
    } else {
#pragma unroll
      for (int r = 0; r < 4; ++r) {
        int c = (t - 8) * 16 + quad * 4 + r;
        vT[((size_t)b * CD + c) * ND + n] = f2bf(O[t][r]);
      }
    }
  }
}

// ---------------------------------------------------------------------------
// k_colsum: partial column sums of exp(e), e = qh*kh + qh*kl (2-product).
// COUNTED-vmcnt barriers; q-tile DMA staged 2-ahead into triple buffer.
// grid 512 (n-split halves), block 128m x 2048n.
// ---------------------------------------------------------------------------
__global__ __launch_bounds__(512, 4) void k_colsum(
    const unsigned short* __restrict__ qh, const unsigned short* __restrict__ khp,
    const unsigned short* __restrict__ klp, float* __restrict__ Dp) {
  const int bid = blockIdx.x, b = bid & 7, half = (bid >> 3) & 1,
            m0 = (bid >> 4) * 128;
  const int nbase = half * 2048;
  const int tid = threadIdx.x, w = tid >> 6, lane = tid & 63, lq = lane & 15,
            quad = lane >> 4;
  const int mq = w & 3, nh = w >> 2;
  __shared__ __align__(16) unsigned short qbuf[3][4096];  // 64n x 64d swizzled
  __shared__ float Cb[128];
  short8v bkh[2][2], bkl[2][2];
#pragma unroll
  for (int sub = 0; sub < 2; ++sub)
#pragma unroll
    for (int k = 0; k < 2; ++k) {
      size_t a = ((size_t)b * ND + m0 + mq * 32 + sub * 16 + lq) * DA + k * 32 + quad * 8;
      bkh[sub][k] = *(const short8v*)(khp + a);
      bkl[sub][k] = *(const short8v*)(klp + a);
    }
  // async staging: 512 chunks/tile, 1 per thread; swizzle baked into source
  const int srow = w * 8 + (lane >> 3), sck = lane & 7;
  auto stageQ = [&](int it, int qn) {
    const unsigned short* src = qh + ((size_t)b * ND + nbase + it * 64 + srow) * DA +
                                ((sck ^ (srow & 7)) << 3);
    gld16(src, &qbuf[qn][0] + (size_t)w * 512);
  };
  stageQ(0, 0);
  stageQ(1, 1);
  // stage(0) retired for everyone; stage(1) still in flight
  asm volatile("s_waitcnt vmcnt(1)\n\ts_barrier" ::: "memory");
  float cs0 = 0.f, cs1 = 0.f;
  int rc = 0, sc = 2;
#pragma unroll 1
  for (int i = 0; i < 32; ++i) {
    if (i < 30) { stageQ(i + 2, sc); sc = (sc + 1 == 3) ? 0 : sc + 1; }
#pragma unroll
    for (int s = 0; s < 2; ++s) {
      short8v ah[2];
#pragma unroll
      for (int k = 0; k < 2; ++k)
        ah[k] = *(const short8v*)&qbuf[rc][sw(nh * 32 + s * 16 + lq, k * 4 + quad)];
#pragma unroll
      for (int sub = 0; sub < 2; ++sub) {
        float4v acc = {0.f, 0.f, 0.f, 0.f};
#pragma unroll
        for (int k = 0; k < 2; ++k) {
          acc = mfma16(ah[k], bkh[sub][k], acc);
          acc = mfma16(ah[k], bkl[sub][k], acc);
        }
        float e0 = __expf(acc[0]) + __expf(acc[1]) + __expf(acc[2]) + __expf(acc[3]);
        if (sub == 0) cs0 += e0; else cs1 += e0;
      }
    }
    rc = (rc + 1 == 3) ? 0 : rc + 1;
    // counted barrier: stage(i+1) (older) retired, stage(i+2) stays in flight
    if (i < 30)
      asm volatile("s_waitcnt vmcnt(1) lgkmcnt(0)\n\ts_barrier" ::: "memory");
    else
      asm volatile("s_waitcnt vmcnt(0) lgkmcnt(0)\n\ts_barrier" ::: "memory");
  }
  cs0 += __shfl_down(cs0, 16); cs0 += __shfl_down(cs0, 32);
  cs1 += __shfl_down(cs1, 16); cs1 += __shfl_down(cs1, 32);
  if (nh == 0 && lane < 16) {
    Cb[mq * 32 + lane] = cs0;
    Cb[mq * 32 + 16 + lane] = cs1;
  }
  __syncthreads();
  if (nh == 1 && lane < 16) {
    float t0 = Cb[mq * 32 + lane] + cs0;
    float t1 = Cb[mq * 32 + 16 + lane] + cs1;
    size_t o = (size_t)half * (BD * ND) + (size_t)b * ND + m0 + mq * 32 + lane;
    Dp[o] = t0;
    Dp[o + 16] = t1;
  }
}

// combine halves: Drec = 1/(Dp0+Dp1). grid 32 x 256.
__global__ void k_rcp(const float* __restrict__ Dp, float* __restrict__ Drec) {
  int i = blockIdx.x * 256 + threadIdx.x;
  float4 a = *(const float4*)&Dp[(size_t)i * 4];
  float4 c = *(const float4*)&Dp[(size_t)(BD * ND) + (size_t)i * 4];
  float4 r;
  r.x = 1.f / (a.x + c.x); r.y = 1.f / (a.y + c.y);
  r.z = 1.f / (a.z + c.z); r.w = 1.f / (a.w + c.w);
  *(float4*)&Drec[(size_t)i * 4] = r;
}

// ---------------------------------------------------------------------------
// k_attn v6: *** in-register P *** — the e->LDS->barrier->PV round trip is
// deleted (R5 post-mortem: that serialization was the remaining 3x over the
// MFMA floor). 8 waves = nh8: each wave owns 16 n (n = n0 + w*16 + lq) and
// the FULL 64-m K-tile:
//   e:  E[64m x 16n] = 4 mtiles x k2 x 2prod = 16 MFMA (no redundancy);
//       lane holds m = mtile*16 + quad*4 + r for its n=lq.
//   P:  exp*drc, truncate-pack to bf16 pairs (bit-identical to R5), then
//       quad-exchange via 16 ds_bpermute + 8 cndmask to PV's A-layout
//       (m = ks*32 + quad*8 + j). Derivation: target (lq,qt) takes
//       u0..u3 from src lanes lq+qs*16, qs=(qt&1)*2{,+1}, reg w{0,1}[2ks+(qt>>1)].
//   PV: O[16ct] over full 256 c, ks2 -> 32 MFMA, 32 swizzled b128 vbuf reads.
//   rs: wave-local (full m in wave) -> 2 shfl_xor; no LDS combine, no Sb.
// LDS = vbuf dbuf only (64 KB). ONE barrier/iter (vmcnt(0): stage spans the
// whole body, ~2600cy >> HBM latency). K reloaded in-place after e (no kn).
// VGPR ~230 @ 2 waves/SIMD. Numerics identical (absmax must stay 0.078125).
// ---------------------------------------------------------------------------
__global__ __launch_bounds__(512, 2) void k_attn(
    const unsigned short* __restrict__ qh, const unsigned short* __restrict__ khp,
    const unsigned short* __restrict__ klp, const unsigned short* __restrict__ vT,
    const float* __restrict__ Drec, unsigned short* xhy,
    const unsigned short* __restrict__ xTl) {
  const int bid = blockIdx.x, b = bid & 7, n0 = (bid >> 3) * 128;
  const int tid = threadIdx.x, w = tid >> 6, lane = tid & 63, lq = lane & 15,
            quad = lane >> 4;
  __shared__ __align__(16) unsigned short vbuf[2][16384];  // 256c x 64m swizzled

  // Q B-frags (hi only): wave's 16-n slice, resident
  short8v aq[2];
#pragma unroll
  for (int k = 0; k < 2; ++k)
    aq[k] = *(const short8v*)(qh + ((size_t)b * ND + n0 + w * 16 + lq) * DA +
                              k * 32 + quad * 8);
  float4v O[16];
#pragma unroll
  for (int ct = 0; ct < 16; ++ct) O[ct] = (float4v){0.f, 0.f, 0.f, 0.f};
  float rs = 0.f;

  // async vT staging: 2048 chunks, 4/thread, swizzle baked into source
  auto stageV = [&](int mtile, int vn) {
    unsigned short* base = &vbuf[vn][0];
#pragma unroll
    for (int j = 0; j < 4; ++j) {
      int cidx = tid + j * 512;
      int row = cidx >> 3, ckpos = cidx & 7;
      const unsigned short* src =
          vT + ((size_t)b * CD + row) * ND + mtile * 64 + ((ckpos ^ (row & 7)) << 3);
      gld16(src, base + (size_t)(w * 64 + j * 512) * 8);
    }
  };
  short8v kc[4][2][2];  // [mtile][k][h|l] — full 64-m K-tile, A-operand rows
  auto kload = [&](int mt) {
#pragma unroll
    for (int mtile = 0; mtile < 4; ++mtile)
#pragma unroll
      for (int k = 0; k < 2; ++k) {
        size_t a = ((size_t)b * ND + mt * 64 + mtile * 16 + lq) * DA + k * 32 + quad * 8;
        kc[mtile][k][0] = *(const short8v*)(khp + a);
        kc[mtile][k][1] = *(const short8v*)(klp + a);
      }
  };
  float4 drc[4];
  auto dload = [&](int mt) {
#pragma unroll
    for (int mtile = 0; mtile < 4; ++mtile)
      drc[mtile] = *(const float4*)&Drec[(size_t)b * ND + mt * 64 + mtile * 16 + quad * 4];
  };
  // bpermute byte addrs (iter-invariant): src quads (quad&1)*2 and +1
  const int bp0 = (lq + ((quad & 1) * 2) * 16) * 4;
  const int bp1 = bp0 + 64;
  const bool hi = (quad >> 1) != 0;

  stageV(0, 0);
  kload(0);
  dload(0);
  asm volatile("s_waitcnt vmcnt(0)\n\ts_barrier" ::: "memory");

#pragma unroll 1
  for (int i = 0; i < 64; ++i) {
    if (i < 63) stageV(i + 1, (i + 1) & 1);
    // ---- e(i): E[64m x 16n], 2-product, swapped operands ----
    float4v acc[4];
#pragma unroll
    for (int mtile = 0; mtile < 4; ++mtile) {
      acc[mtile] = (float4v){0.f, 0.f, 0.f, 0.f};
#pragma unroll
      for (int k = 0; k < 2; ++k) {
        acc[mtile] = mfma16(kc[mtile][k][0], aq[k], acc[mtile]);
        acc[mtile] = mfma16(kc[mtile][k][1], aq[k], acc[mtile]);
      }
    }
    if (i < 63) kload(i + 1);  // kc free after e(i); consumed after barrier
    // ---- P = trunc_bf16(exp(E)*drc), packed pairs (bit-identical to R5) ----
    unsigned int w0[4], w1[4];
#pragma unroll
    for (int mtile = 0; mtile < 4; ++mtile) {
      float p0 = __expf(acc[mtile][0]) * drc[mtile].x;
      float p1 = __expf(acc[mtile][1]) * drc[mtile].y;
      float p2 = __expf(acc[mtile][2]) * drc[mtile].z;
      float p3 = __expf(acc[mtile][3]) * drc[mtile].w;
      rs += (p0 + p1) + (p2 + p3);
      w0[mtile] = (__float_as_uint(p0) >> 16) | (__float_as_uint(p1) & 0xffff0000u);
      w1[mtile] = (__float_as_uint(p2) >> 16) | (__float_as_uint(p3) & 0xffff0000u);
    }
    if (i < 63) dload(i + 1);  // drc free after pack
    // ---- quad-exchange: (m=mtile*16+quad*4+r) -> ap[ks] (m=ks*32+quad*8+j) ----
    short8v ap[2];
#pragma unroll
    for (int ks = 0; ks < 2; ++ks) {
      int a0 = __builtin_amdgcn_ds_bpermute(bp0, (int)w0[2 * ks]);
      int b0 = __builtin_amdgcn_ds_bpermute(bp0, (int)w1[2 * ks]);
      int c0 = __builtin_amdgcn_ds_bpermute(bp0, (int)w0[2 * ks + 1]);
      int d0 = __builtin_amdgcn_ds_bpermute(bp0, (int)w1[2 * ks + 1]);
      int a1 = __builtin_amdgcn_ds_bpermute(bp1, (int)w0[2 * ks]);
      int b1 = __builtin_amdgcn_ds_bpermute(bp1, (int)w1[2 * ks]);
      int c1 = __builtin_amdgcn_ds_bpermute(bp1, (int)w0[2 * ks + 1]);
      int d1 = __builtin_amdgcn_ds_bpermute(bp1, (int)w1[2 * ks + 1]);
      uint4 u;
      u.x = (unsigned int)(hi ? c0 : a0);
      u.y = (unsigned int)(hi ? d0 : b0);
      u.z = (unsigned int)(hi ? c1 : a1);
      u.w = (unsigned int)(hi ? d1 : b1);
      union { uint4 u4; short8v s8; } cvt; cvt.u4 = u;
      ap[ks] = cvt.s8;
    }
    // ---- PV(i): O[16ct] += V(c rows) x P(n cols), full 256 c ----
    const unsigned short* vc = &vbuf[i & 1][0];
#pragma unroll
    for (int ct = 0; ct < 16; ++ct) {
      const int trow = ct * 16 + lq;
#pragma unroll
      for (int ks = 0; ks < 2; ++ks) {
        short8v bv = *(const short8v*)&vc[sw(trow, ks * 4 + quad)];
        O[ct] = mfma16(bv, ap[ks], O[ct]);
      }
    }
    // single barrier: drains stage(i+1) (whole body of latency), kc, drc;
    // lgkmcnt(0) retires PV reads of vbuf[i&1] before it is restaged.
    if (i < 63)
      asm volatile("s_waitcnt vmcnt(0) lgkmcnt(0)\n\ts_barrier" ::: "memory");
  }

  // ---- rs: wave-local full-m sum -> quad butterfly only ----
  rs += __shfl_xor(rs, 16);
  rs += __shfl_xor(rs, 32);
  const float rsc = 1.0f / (1e-9f + rs);
  // ---- y = x - O/S, in place over xTh (lane: 4 consecutive c, fixed n) ----
  const int n = n0 + w * 16 + lq;
#pragma unroll
  for (int ct = 0; ct < 16; ++ct) {
    const int cb = ct * 16 + quad * 4;
    const size_t off = ((size_t)b * ND + n) * CD + cb;
    ushort4 h4 = *(const ushort4*)&xhy[off];
    ushort4 l4 = *(const ushort4*)&xTl[off];
    ushort4 o4;
    o4.x = f2bf(bf2f(h4.x) + bf2f(l4.x) - O[ct][0] * rsc);
    o4.y = f2bf(bf2f(h4.y) + bf2f(l4.y) - O[ct][1] * rsc);
    o4.z = f2bf(bf2f(h4.z) + bf2f(l4.z) - O[ct][2] * rsc);
    o4.w = f2bf(bf2f(h4.w) + bf2f(l4.w) - O[ct][3] * rsc);
    *(ushort4*)&xhy[off] = o4;
  }
}

// ---------------------------------------------------------------------------
// k_final: h = Wp . y (bf16 MFMA); out = relu(BN(h)) + x.
// ---------------------------------------------------------------------------
__global__ __launch_bounds__(256) void k_final(const unsigned short* __restrict__ y,
                                               const unsigned short* __restrict__ Wpb,
                                               const float* __restrict__ x,
                                               const float* __restrict__ gamma,
                                               const float* __restrict__ beta,
                                               const float* __restrict__ mean,
                                               const float* __restrict__ var,
                                               float* __restrict__ out) {
  const int bid = blockIdx.x;
  const int b = bid & 7;
  const int rem = bid >> 3;
  const int n0 = (rem & 63) * 64;
  const int d0 = (rem >> 6) * 64;
  const int tid = threadIdx.x;
  const int wave = tid >> 6, lane = tid & 63, lq = lane & 15, quad = lane >> 4;
  const int dw = d0 + wave * 16;
  float4v O[4];
#pragma unroll
  for (int s = 0; s < 4; ++s) O[s] = (float4v){0.f, 0.f, 0.f, 0.f};
#pragma unroll
  for (int chh = 0; chh < 8; ++chh) {
    const size_t ab = (size_t)(dw + lq) * CD + chh * 32 + quad * 8;
    short8v a0 = *(const short8v*)(Wpb + ab);
#pragma unroll
    for (int s = 0; s < 4; ++s) {
      const size_t bb = ((size_t)b * ND + n0 + s * 16 + lq) * CD + chh * 32 + quad * 8;
      short8v bv = *(const short8v*)(y + bb);
      O[s] = mfma16(a0, bv, O[s]);
    }
  }
#pragma unroll
  for (int r = 0; r < 4; ++r) {
    const int d = dw + quad * 4 + r;
    const float inv  = gamma[d] / sqrtf(var[d] + 1e-5f);
    const float bias = beta[d] - mean[d] * inv;
#pragma unroll
    for (int s = 0; s < 4; ++s) {
      const int n = n0 + s * 16 + lq;
      const size_t oi = ((size_t)b * CD + d) * ND + n;
      out[oi] = fmaxf(O[s][r] * inv + bias, 0.f) + x[oi];
    }
  }
}

extern "C" void kernel_launch(void* const* d_in, const int* in_sizes, int n_in,
                              void* d_out, int out_size, void* d_ws, size_t ws_size,
                              hipStream_t stream) {
  const float* x     = (const float*)d_in[0];
  const float* Wq    = (const float*)d_in[1];
  const float* Wk    = (const float*)d_in[2];
  const float* Wv    = (const float*)d_in[3];
  const float* Wp    = (const float*)d_in[4];
  const float* gamma = (const float*)d_in[5];
  const float* beta  = (const float*)d_in[6];
  const float* mean  = (const float*)d_in[7];
  const float* var   = (const float*)d_in[8];
  float* out = (float*)d_out;

  char* wsp = (char*)d_ws;
  unsigned short* qhp = (unsigned short*)wsp; wsp += (size_t)BD * ND * DA * 2;
  unsigned short* khp = (unsigned short*)wsp; wsp += (size_t)BD * ND * DA * 2;
  unsigned short* klp = (unsigned short*)wsp; wsp += (size_t)BD * ND * DA * 2;
  unsigned short* vT  = (unsigned short*)wsp; wsp += (size_t)BD * CD * ND * 2;
  unsigned short* xTh = (unsigned short*)wsp; wsp += (size_t)BD * ND * CD * 2;  // aliased as y
  unsigned short* xTl = (unsigned short*)wsp; wsp += (size_t)BD * ND * CD * 2;
  unsigned short* Wch = (unsigned short*)wsp; wsp += (size_t)384 * 256 * 2;
  unsigned short* Wcl = (unsigned short*)wsp; wsp += (size_t)384 * 256 * 2;
  unsigned short* Wph = (unsigned short*)wsp; wsp += (size_t)256 * 256 * 2;
  unsigned short* Wpl = (unsigned short*)wsp; wsp += (size_t)256 * 256 * 2;
  float* Drec = (float*)wsp; wsp += (size_t)BD * ND * 4;
  float* Dp   = (float*)wsp; wsp += (size_t)2 * BD * ND * 4;
  unsigned short* y = xTh;  // xTh consumed+overwritten by k_attn epilogue

  dim3 blk(256), blk5(512);
  k_prep<<<dim3(ND / 64, CD / 64, BD), blk, 0, stream>>>(x, xTh, xTl);
  k_prepW<<<dim3(160), blk, 0, stream>>>(Wq, Wk, Wv, Wp, Wch, Wcl, Wph, Wpl);
  k_proj<<<dim3(ND / 128, BD), blk5, 0, stream>>>(xTh, xTl, Wch, Wcl, qhp, khp,
                                                  klp, vT);
  k_colsum<<<dim3(512), blk5, 0, stream>>>(qhp, khp, klp, Dp);
  k_rcp<<<dim3(32), blk, 0, stream>>>(Dp, Drec);
  k_attn<<<dim3(256), blk5, 0, stream>>>(qhp, khp, klp, vT, Drec, y, xTl);
  k_final<<<dim3(2048), blk, 0, stream>>>(y, Wph, x, gamma, beta, mean, var, out);
}

// Round 8
// 510.154 us; speedup vs baseline: 1.1612x; 1.1612x over previous
//
#include <hip/hip_runtime.h>
#include <math.h>

#define BD 8
#define CD 256
#define ND 4096
#define DA 64

typedef __attribute__((ext_vector_type(8))) short short8v;
typedef __attribute__((ext_vector_type(4))) float float4v;
typedef __attribute__((ext_vector_type(16))) float f32x16;

static __device__ __forceinline__ float4v mfma16(short8v a, short8v b, float4v c) {
  return __builtin_amdgcn_mfma_f32_16x16x32_bf16(a, b, c, 0, 0, 0);
}
static __device__ __forceinline__ f32x16 mfma32(short8v a, short8v b, f32x16 c) {
  return __builtin_amdgcn_mfma_f32_32x32x16_bf16(a, b, c, 0, 0, 0);
}
static __device__ __forceinline__ unsigned short f2bf(float f) {
  union { float f; unsigned int u; } v; v.f = f;
  return (unsigned short)((v.u + 0x7fffu + ((v.u >> 16) & 1u)) >> 16);
}
static __device__ __forceinline__ float bf2f(unsigned short h) {
  union { unsigned int u; float f; } v; v.u = (unsigned int)h << 16;
  return v.f;
}
// XOR-swizzled LDS offset (ushort units) for rows of 64 bf16 (8 x 16B chunks).
static __device__ __forceinline__ int sw(int row, int c8) {
  return row * 64 + (((c8) ^ (row & 7)) << 3);
}
typedef const __attribute__((address_space(1))) unsigned int g_u32;
typedef __attribute__((address_space(3))) unsigned int l_u32;
static __device__ __forceinline__ void gld16(const void* g, void* l) {
  __builtin_amdgcn_global_load_lds((g_u32*)g, (l_u32*)l, 16, 0, 0);
}

// ---------------------------------------------------------------------------
// k_prep: x [b][c][n] fp32 -> xTh/xTl [b][n][256] split bf16 (transposed).
// ---------------------------------------------------------------------------
__global__ __launch_bounds__(256) void k_prep(const float* __restrict__ x,
                                              unsigned short* __restrict__ xTh,
                                              unsigned short* __restrict__ xTl) {
  const int n0 = blockIdx.x * 64, c0 = blockIdx.y * 64, b = blockIdx.z;
  __shared__ float Xs[64][68];
  const int tid = threadIdx.x;
  const int r0 = tid >> 4, col4 = (tid & 15) * 4;
#pragma unroll
  for (int j = 0; j < 4; ++j) {
    int r = r0 + j * 16;
    *(float4*)&Xs[r][col4] =
        *(const float4*)&x[((size_t)(b * CD + c0 + r)) * ND + n0 + col4];
  }
  __syncthreads();
  const int n = tid >> 2, cg = (tid & 3) * 16;
  unsigned short h[16], l[16];
#pragma unroll
  for (int j = 0; j < 16; ++j) {
    float v = Xs[cg + j][n];
    h[j] = f2bf(v);
    l[j] = f2bf(v - bf2f(h[j]));
  }
  size_t o = ((size_t)b * ND + n0 + n) * CD + c0 + cg;
#pragma unroll
  for (int j = 0; j < 4; ++j) {
    *(ushort4*)&xTh[o + j * 4] = *(ushort4*)&h[j * 4];
    *(ushort4*)&xTl[o + j * 4] = *(ushort4*)&l[j * 4];
  }
}

// ---------------------------------------------------------------------------
// k_prepW: split weights fp32 -> bf16 hi/lo. Wch/Wcl = [Wq;Wk;Wv] rows 0..383.
// ---------------------------------------------------------------------------
__global__ void k_prepW(const float* __restrict__ Wq, const float* __restrict__ Wk,
                        const float* __restrict__ Wv, const float* __restrict__ Wp,
                        unsigned short* Wch, unsigned short* Wcl,
                        unsigned short* Wph, unsigned short* Wpl) {
  int i = blockIdx.x * 256 + threadIdx.x;  // 640 rows x 64 float4
  int row = i >> 6, c4 = (i & 63) * 4;
  const float* src; unsigned short *dh, *dl; int r, drow;
  if (row < 64)       { src = Wq; r = row;       dh = Wch; dl = Wcl; drow = row; }
  else if (row < 128) { src = Wk; r = row - 64;  dh = Wch; dl = Wcl; drow = row; }
  else if (row < 384) { src = Wv; r = row - 128; dh = Wch; dl = Wcl; drow = row; }
  else                { src = Wp; r = row - 384; dh = Wph; dl = Wpl; drow = row - 384; }
  float4 f = *(const float4*)&src[(size_t)r * 256 + c4];
  ushort4 hh, ll;
  hh.x = f2bf(f.x); hh.y = f2bf(f.y); hh.z = f2bf(f.z); hh.w = f2bf(f.w);
  ll.x = f2bf(f.x - bf2f(hh.x)); ll.y = f2bf(f.y - bf2f(hh.y));
  ll.z = f2bf(f.z - bf2f(hh.z)); ll.w = f2bf(f.w - bf2f(hh.w));
  *(ushort4*)&dh[(size_t)drow * 256 + c4] = hh;
  *(ushort4*)&dl[(size_t)drow * 256 + c4] = ll;
}

// ---------------------------------------------------------------------------
// k_proj: MERGED q/k/v projection (reads xT once, LDS k-slices, 3-product).
// grid (ND/128, B), 512 thr. q: hi only; k: hi+lo; v: transposed bf16.
// ---------------------------------------------------------------------------
__global__ __launch_bounds__(512) void k_proj(
    const unsigned short* __restrict__ xTh, const unsigned short* __restrict__ xTl,
    const unsigned short* __restrict__ Wch, const unsigned short* __restrict__ Wcl,
    unsigned short* __restrict__ qh, unsigned short* __restrict__ kh,
    unsigned short* __restrict__ kl, unsigned short* __restrict__ vT) {
  const int n0 = blockIdx.x * 128, b = blockIdx.y;
  const int tid = threadIdx.x, w = tid >> 6, lane = tid & 63, lq = lane & 15,
            quad = lane >> 4;
  __shared__ __align__(16) unsigned short xs[2][2][128][40];
  float4v O[24];
#pragma unroll
  for (int t = 0; t < 24; ++t) O[t] = (float4v){0.f, 0.f, 0.f, 0.f};

  const int srow = tid >> 2, sc4 = tid & 3;
  uint4 rh, rl;
  auto load_slice = [&](int ks) {
    size_t a = ((size_t)b * ND + n0 + srow) * CD + ks * 32 + sc4 * 8;
    rh = *(const uint4*)(xTh + a);
    rl = *(const uint4*)(xTl + a);
  };
  auto write_slice = [&](int buf) {
    *(uint4*)&xs[buf][0][srow][sc4 * 8] = rh;
    *(uint4*)&xs[buf][1][srow][sc4 * 8] = rl;
  };
  load_slice(0); write_slice(0);
#pragma unroll 1
  for (int ks = 0; ks < 8; ++ks) {
    __syncthreads();
    if (ks < 7) load_slice(ks + 1);
    short8v bxh = *(const short8v*)&xs[ks & 1][0][w * 16 + lq][quad * 8];
    short8v bxl = *(const short8v*)&xs[ks & 1][1][w * 16 + lq][quad * 8];
#pragma unroll
    for (int t = 0; t < 24; ++t) {
      size_t a = (size_t)(t * 16 + lq) * CD + ks * 32 + quad * 8;
      short8v awh = *(const short8v*)(Wch + a);
      short8v awl = *(const short8v*)(Wcl + a);
      O[t] = mfma16(awh, bxh, O[t]);
      O[t] = mfma16(awl, bxh, O[t]);
      O[t] = mfma16(awh, bxl, O[t]);
    }
    if (ks < 7) write_slice((ks + 1) & 1);
  }
  const int n = n0 + w * 16 + lq;
#pragma unroll
  for (int t = 0; t < 24; ++t) {
    if (t < 4) {
      ushort4 hh;
      hh.x = f2bf(O[t][0]); hh.y = f2bf(O[t][1]);
      hh.z = f2bf(O[t][2]); hh.w = f2bf(O[t][3]);
      *(ushort4*)&qh[((size_t)b * ND + n) * DA + t * 16 + quad * 4] = hh;
    } else if (t < 8) {
      ushort4 hh, ll;
      hh.x = f2bf(O[t][0]); hh.y = f2bf(O[t][1]);
      hh.z = f2bf(O[t][2]); hh.w = f2bf(O[t][3]);
      ll.x = f2bf(O[t][0] - bf2f(hh.x)); ll.y = f2bf(O[t][1] - bf2f(hh.y));
      ll.z = f2bf(O[t][2] - bf2f(hh.z)); ll.w = f2bf(O[t][3] - bf2f(hh.w));
      size_t o = ((size_t)b * ND + n) * DA + (t - 4) * 16 + quad * 4;
      *(ushort4*)&kh[o] = hh;
      *(ushort4*)&kl[o] = ll;
    } else {
#pragma unroll
      for (int r = 0; r < 4; ++r) {
        int c = (t - 8) * 16 + quad * 4 + r;
        vT[((size_t)b * CD + c) * ND + n] = f2bf(O[t][r]);
      }
    }
  }
}

// ---------------------------------------------------------------------------
// k_colsum: partial column sums of exp(e), e = qh*kh + qh*kl (2-product).
// COUNTED-vmcnt barriers; q-tile DMA staged 2-ahead into triple buffer.
// grid 512 (n-split halves), block 128m x 2048n.
// ---------------------------------------------------------------------------
__global__ __launch_bounds__(512, 4) void k_colsum(
    const unsigned short* __restrict__ qh, const unsigned short* __restrict__ khp,
    const unsigned short* __restrict__ klp, float* __restrict__ Dp) {
  const int bid = blockIdx.x, b = bid & 7, half = (bid >> 3) & 1,
            m0 = (bid >> 4) * 128;
  const int nbase = half * 2048;
  const int tid = threadIdx.x, w = tid >> 6, lane = tid & 63, lq = lane & 15,
            quad = lane >> 4;
  const int mq = w & 3, nh = w >> 2;
  __shared__ __align__(16) unsigned short qbuf[3][4096];  // 64n x 64d swizzled
  __shared__ float Cb[128];
  short8v bkh[2][2], bkl[2][2];
#pragma unroll
  for (int sub = 0; sub < 2; ++sub)
#pragma unroll
    for (int k = 0; k < 2; ++k) {
      size_t a = ((size_t)b * ND + m0 + mq * 32 + sub * 16 + lq) * DA + k * 32 + quad * 8;
      bkh[sub][k] = *(const short8v*)(khp + a);
      bkl[sub][k] = *(const short8v*)(klp + a);
    }
  // async staging: 512 chunks/tile, 1 per thread; swizzle baked into source
  const int srow = w * 8 + (lane >> 3), sck = lane & 7;
  auto stageQ = [&](int it, int qn) {
    const unsigned short* src = qh + ((size_t)b * ND + nbase + it * 64 + srow) * DA +
                                ((sck ^ (srow & 7)) << 3);
    gld16(src, &qbuf[qn][0] + (size_t)w * 512);
  };
  stageQ(0, 0);
  stageQ(1, 1);
  // stage(0) retired for everyone; stage(1) still in flight
  asm volatile("s_waitcnt vmcnt(1)\n\ts_barrier" ::: "memory");
  float cs0 = 0.f, cs1 = 0.f;
  int rc = 0, sc = 2;
#pragma unroll 1
  for (int i = 0; i < 32; ++i) {
    if (i < 30) { stageQ(i + 2, sc); sc = (sc + 1 == 3) ? 0 : sc + 1; }
#pragma unroll
    for (int s = 0; s < 2; ++s) {
      short8v ah[2];
#pragma unroll
      for (int k = 0; k < 2; ++k)
        ah[k] = *(const short8v*)&qbuf[rc][sw(nh * 32 + s * 16 + lq, k * 4 + quad)];
#pragma unroll
      for (int sub = 0; sub < 2; ++sub) {
        float4v acc = {0.f, 0.f, 0.f, 0.f};
#pragma unroll
        for (int k = 0; k < 2; ++k) {
          acc = mfma16(ah[k], bkh[sub][k], acc);
          acc = mfma16(ah[k], bkl[sub][k], acc);
        }
        float e0 = __expf(acc[0]) + __expf(acc[1]) + __expf(acc[2]) + __expf(acc[3]);
        if (sub == 0) cs0 += e0; else cs1 += e0;
      }
    }
    rc = (rc + 1 == 3) ? 0 : rc + 1;
    // counted barrier: stage(i+1) (older) retired, stage(i+2) stays in flight
    if (i < 30)
      asm volatile("s_waitcnt vmcnt(1) lgkmcnt(0)\n\ts_barrier" ::: "memory");
    else
      asm volatile("s_waitcnt vmcnt(0) lgkmcnt(0)\n\ts_barrier" ::: "memory");
  }
  cs0 += __shfl_down(cs0, 16); cs0 += __shfl_down(cs0, 32);
  cs1 += __shfl_down(cs1, 16); cs1 += __shfl_down(cs1, 32);
  if (nh == 0 && lane < 16) {
    Cb[mq * 32 + lane] = cs0;
    Cb[mq * 32 + 16 + lane] = cs1;
  }
  __syncthreads();
  if (nh == 1 && lane < 16) {
    float t0 = Cb[mq * 32 + lane] + cs0;
    float t1 = Cb[mq * 32 + 16 + lane] + cs1;
    size_t o = (size_t)half * (BD * ND) + (size_t)b * ND + m0 + mq * 32 + lane;
    Dp[o] = t0;
    Dp[o + 16] = t1;
  }
}

// combine halves: Drec = 1/(Dp0+Dp1). grid 32 x 256.
__global__ void k_rcp(const float* __restrict__ Dp, float* __restrict__ Drec) {
  int i = blockIdx.x * 256 + threadIdx.x;
  float4 a = *(const float4*)&Dp[(size_t)i * 4];
  float4 c = *(const float4*)&Dp[(size_t)(BD * ND) + (size_t)i * 4];
  float4 r;
  r.x = 1.f / (a.x + c.x); r.y = 1.f / (a.y + c.y);
  r.z = 1.f / (a.z + c.z); r.w = 1.f / (a.w + c.w);
  *(float4*)&Drec[(size_t)i * 4] = r;
}

// ---------------------------------------------------------------------------
// k_attn v8: v7 (32x32 MFMA, in-register P, lane-local hi-half shfl exchange)
// + the FIX for R7's correctness bug: each wave's O is a partial sum over its
// own 32-m half (mh), so the two mh waves of each nq MUST be combined before
// the epilogue. R7 had both halves racing on the same output. Now: after the
// loop, mh=1 waves dump O into the freed vbuf LDS (two 4-ct chunks of 64KB),
// mh=0 waves add and alone run the y-epilogue. Everything else identical to
// v7 (R5 skeleton: triple vbuf, counted vmcnt(4), kc/dr in-place reload).
// ---------------------------------------------------------------------------
__global__ __launch_bounds__(512, 2) void k_attn(
    const unsigned short* __restrict__ qh, const unsigned short* __restrict__ khp,
    const unsigned short* __restrict__ klp, const unsigned short* __restrict__ vT,
    const float* __restrict__ Drec, unsigned short* xhy,
    const unsigned short* __restrict__ xTl) {
  const int bid = blockIdx.x, b = bid & 7, n0 = (bid >> 3) * 128;
  const int tid = threadIdx.x, w = tid >> 6, lane = tid & 63;
  const int l32 = lane & 31, hi = lane >> 5;
  const int mh = w & 1, nq = w >> 1;  // 2 m-halves x 4 n-quarters
  __shared__ __align__(16) unsigned short vbuf[3][16384];  // 256c x 64m swizzled
  __shared__ float Sb[2][128];

  // Q B-frags (hi only): col n = n0+nq*32+l32, k(d) = kk*16 + hi*8 + j
  short8v aq[4];
#pragma unroll
  for (int kk = 0; kk < 4; ++kk)
    aq[kk] = *(const short8v*)(qh + ((size_t)b * ND + n0 + nq * 32 + l32) * DA +
                               kk * 16 + hi * 8);
  f32x16 O[8];
  const f32x16 z16 = {0.f, 0.f, 0.f, 0.f, 0.f, 0.f, 0.f, 0.f,
                      0.f, 0.f, 0.f, 0.f, 0.f, 0.f, 0.f, 0.f};
#pragma unroll
  for (int ct = 0; ct < 8; ++ct) O[ct] = z16;
  float rs = 0.f;

  // async vT staging: 2048 chunks, 4/thread, swizzle baked into source
  auto stageV = [&](int mt, int vn) {
    unsigned short* base = &vbuf[vn][0];
#pragma unroll
    for (int j = 0; j < 4; ++j) {
      int cidx = tid + j * 512;
      int row = cidx >> 3, ckpos = cidx & 7;
      const unsigned short* src =
          vT + ((size_t)b * CD + row) * ND + mt * 64 + ((ckpos ^ (row & 7)) << 3);
      gld16(src, base + (size_t)(w * 64 + j * 512) * 8);
    }
  };
  // K A-frags: rows m = mt*64 + mh*32 + l32, k(d) = kk*16 + hi*8 + j
  short8v kc[4][2];
  auto kload = [&](int mt) {
#pragma unroll
    for (int kk = 0; kk < 4; ++kk) {
      size_t a = ((size_t)b * ND + mt * 64 + mh * 32 + l32) * DA + kk * 16 + hi * 8;
      kc[kk][0] = *(const short8v*)(khp + a);
      kc[kk][1] = *(const short8v*)(klp + a);
    }
  };
  // dr[r] = Drec[m(r)], m(r) = (r&3) + 8*(r>>2) + 4*hi (+ mh*32 + mt*64)
  float dr[16];
  auto dload = [&](int mt) {
#pragma unroll
    for (int g = 0; g < 4; ++g) {
      float4 t = *(const float4*)&Drec[(size_t)b * ND + mt * 64 + mh * 32 +
                                       g * 8 + hi * 4];
      dr[g * 4 + 0] = t.x; dr[g * 4 + 1] = t.y;
      dr[g * 4 + 2] = t.z; dr[g * 4 + 3] = t.w;
    }
  };
  short8v pf[2];  // P B-frags, persist across the barrier (PV deferred 1 body)
  auto doPV = [&](const unsigned short* vc) {
#pragma unroll
    for (int ct = 0; ct < 8; ++ct) {
      const int row = ct * 32 + l32;
#pragma unroll
      for (int kk2 = 0; kk2 < 2; ++kk2) {
        short8v bv = *(const short8v*)&vc[sw(row, mh * 4 + kk2 * 2 + hi)];
        O[ct] = mfma32(bv, pf[kk2], O[ct]);
      }
    }
  };

  stageV(0, 0);
  kload(0);
  dload(0);

  int vs = 1, vp = 0;
#pragma unroll 1
  for (int i = 0; i < 64; ++i) {
    if (i > 0) {
      doPV(&vbuf[vp][0]);
      vp = (vp + 1 == 3) ? 0 : vp + 1;
    }
    // ---- e(i): E[32m x 32n], 2-product, swapped operands ----
    f32x16 acc = z16;
#pragma unroll
    for (int kk = 0; kk < 4; ++kk) {
      acc = mfma32(kc[kk][0], aq[kk], acc);
      acc = mfma32(kc[kk][1], aq[kk], acc);
    }
    // ---- P = trunc_bf16(exp(E)*drc), packed pairs (bit-identical to R5) ----
    unsigned int pw[8];
#pragma unroll
    for (int j = 0; j < 8; ++j) {
      float pa = __expf(acc[2 * j]) * dr[2 * j];
      float pb = __expf(acc[2 * j + 1]) * dr[2 * j + 1];
      rs += pa + pb;
      pw[j] = (__float_as_uint(pa) >> 16) | (__float_as_uint(pb) & 0xffff0000u);
    }
    // ---- hi-half exchange: 8 shfl_xor(32) + cndmask -> PV B-frags ----
    // word j holds m-pairs: j0:(0,1) j1:(2,3) j2:(8,9) j3:(10,11)
    //                       j4:(16,17) j5:(18,19) j6:(24,25) j7:(26,27) (+4hi)
    {
      unsigned int xw[8];
#pragma unroll
      for (int j = 0; j < 8; ++j) xw[j] = (unsigned int)__shfl_xor((int)pw[j], 32);
      uint4 u0, u1;
      u0.x = hi ? xw[2] : pw[0]; u0.y = hi ? xw[3] : pw[1];
      u0.z = hi ? pw[2] : xw[0]; u0.w = hi ? pw[3] : xw[1];
      u1.x = hi ? xw[6] : pw[4]; u1.y = hi ? xw[7] : pw[5];
      u1.z = hi ? pw[6] : xw[4]; u1.w = hi ? pw[7] : xw[5];
      union { uint4 u4; short8v s8; } c0, c1;
      c0.u4 = u0; c1.u4 = u1;
      pf[0] = c0.s8;  // k = m 0..15  (of wave's 32-m half)
      pf[1] = c1.s8;  // k = m 16..31
    }
    if (i < 63) {
      kload(i + 1);   // kc consumed by e(i) above; retired by barrier vmcnt(4)
      dload(i + 1);   // dr consumed by pack above
      stageV(i + 1, vs);  // newest 4 vmem ops -> stay in flight across barrier
      vs = (vs + 1 == 3) ? 0 : vs + 1;
    }
    // counted barrier: keep THIS body's 4 stage chunks in flight (consumed at
    // body(i+2)); kload/dload/stage(i) all older -> retired.
    if (i < 63)
      asm volatile("s_waitcnt vmcnt(4) lgkmcnt(0)\n\ts_barrier" ::: "memory");
    else
      asm volatile("s_waitcnt vmcnt(0) lgkmcnt(0)\n\ts_barrier" ::: "memory");
  }
  doPV(&vbuf[vp][0]);  // PV(63)

  // ---- rs: hi-half fold, then 2-way mh combine in LDS ----
  rs += __shfl_xor(rs, 32);
  if (lane < 32) Sb[mh][nq * 32 + lane] = rs;

  // ---- O combine across mh (R7 FIX): vbuf is free after PV(63). ----
  // mh=1 stores O chunk to LDS; mh=0 adds. Two chunks of 4 ct (64KB each).
  float* scratch = (float*)&vbuf[0][0];
  __syncthreads();  // PV(63) LDS reads done; Sb visible
#pragma unroll
  for (int half = 0; half < 2; ++half) {
    if (mh == 1) {
#pragma unroll
      for (int ct = 0; ct < 4; ++ct) {
        const int idx = ((nq * 4 + ct) * 64 + lane) * 16;
#pragma unroll
        for (int g = 0; g < 4; ++g) {
          float4 t;
          t.x = O[half * 4 + ct][g * 4 + 0];
          t.y = O[half * 4 + ct][g * 4 + 1];
          t.z = O[half * 4 + ct][g * 4 + 2];
          t.w = O[half * 4 + ct][g * 4 + 3];
          *(float4*)&scratch[idx + g * 4] = t;
        }
      }
    }
    __syncthreads();
    if (mh == 0) {
#pragma unroll
      for (int ct = 0; ct < 4; ++ct) {
        const int idx = ((nq * 4 + ct) * 64 + lane) * 16;
#pragma unroll
        for (int g = 0; g < 4; ++g) {
          float4 t = *(const float4*)&scratch[idx + g * 4];
          O[half * 4 + ct][g * 4 + 0] += t.x;
          O[half * 4 + ct][g * 4 + 1] += t.y;
          O[half * 4 + ct][g * 4 + 2] += t.z;
          O[half * 4 + ct][g * 4 + 3] += t.w;
        }
      }
    }
    __syncthreads();
  }

  const int nl = nq * 32 + l32;
  const float rsc = 1.0f / (1e-9f + Sb[0][nl] + Sb[1][nl]);
  // ---- y = x - O/S (mh=0 waves only; O now the full m-sum) ----
  if (mh == 0) {
    const int n = n0 + nq * 32 + l32;
#pragma unroll
    for (int ct = 0; ct < 8; ++ct) {
#pragma unroll
      for (int g = 0; g < 4; ++g) {
        const int cb = ct * 32 + g * 8 + hi * 4;
        const size_t off = ((size_t)b * ND + n) * CD + cb;
        ushort4 h4 = *(const ushort4*)&xhy[off];
        ushort4 l4 = *(const ushort4*)&xTl[off];
        ushort4 o4;
        o4.x = f2bf(bf2f(h4.x) + bf2f(l4.x) - O[ct][g * 4 + 0] * rsc);
        o4.y = f2bf(bf2f(h4.y) + bf2f(l4.y) - O[ct][g * 4 + 1] * rsc);
        o4.z = f2bf(bf2f(h4.z) + bf2f(l4.z) - O[ct][g * 4 + 2] * rsc);
        o4.w = f2bf(bf2f(h4.w) + bf2f(l4.w) - O[ct][g * 4 + 3] * rsc);
        *(ushort4*)&xhy[off] = o4;
      }
    }
  }
}

// ---------------------------------------------------------------------------
// k_final: h = Wp . y (bf16 MFMA); out = relu(BN(h)) + x.
// ---------------------------------------------------------------------------
__global__ __launch_bounds__(256) void k_final(const unsigned short* __restrict__ y,
                                               const unsigned short* __restrict__ Wpb,
                                               const float* __restrict__ x,
                                               const float* __restrict__ gamma,
                                               const float* __restrict__ beta,
                                               const float* __restrict__ mean,
                                               const float* __restrict__ var,
                                               float* __restrict__ out) {
  const int bid = blockIdx.x;
  const int b = bid & 7;
  const int rem = bid >> 3;
  const int n0 = (rem & 63) * 64;
  const int d0 = (rem >> 6) * 64;
  const int tid = threadIdx.x;
  const int wave = tid >> 6, lane = tid & 63, lq = lane & 15, quad = lane >> 4;
  const int dw = d0 + wave * 16;
  float4v O[4];
#pragma unroll
  for (int s = 0; s < 4; ++s) O[s] = (float4v){0.f, 0.f, 0.f, 0.f};
#pragma unroll
  for (int chh = 0; chh < 8; ++chh) {
    const size_t ab = (size_t)(dw + lq) * CD + chh * 32 + quad * 8;
    short8v a0 = *(const short8v*)(Wpb + ab);
#pragma unroll
    for (int s = 0; s < 4; ++s) {
      const size_t bb = ((size_t)b * ND + n0 + s * 16 + lq) * CD + chh * 32 + quad * 8;
      short8v bv = *(const short8v*)(y + bb);
      O[s] = mfma16(a0, bv, O[s]);
    }
  }
#pragma unroll
  for (int r = 0; r < 4; ++r) {
    const int d = dw + quad * 4 + r;
    const float inv  = gamma[d] / sqrtf(var[d] + 1e-5f);
    const float bias = beta[d] - mean[d] * inv;
#pragma unroll
    for (int s = 0; s < 4; ++s) {
      const int n = n0 + s * 16 + lq;
      const size_t oi = ((size_t)b * CD + d) * ND + n;
      out[oi] = fmaxf(O[s][r] * inv + bias, 0.f) + x[oi];
    }
  }
}

extern "C" void kernel_launch(void* const* d_in, const int* in_sizes, int n_in,
                              void* d_out, int out_size, void* d_ws, size_t ws_size,
                              hipStream_t stream) {
  const float* x     = (const float*)d_in[0];
  const float* Wq    = (const float*)d_in[1];
  const float* Wk    = (const float*)d_in[2];
  const float* Wv    = (const float*)d_in[3];
  const float* Wp    = (const float*)d_in[4];
  const float* gamma = (const float*)d_in[5];
  const float* beta  = (const float*)d_in[6];
  const float* mean  = (const float*)d_in[7];
  const float* var   = (const float*)d_in[8];
  float* out = (float*)d_out;

  char* wsp = (char*)d_ws;
  unsigned short* qhp = (unsigned short*)wsp; wsp += (size_t)BD * ND * DA * 2;
  unsigned short* khp = (unsigned short*)wsp; wsp += (size_t)BD * ND * DA * 2;
  unsigned short* klp = (unsigned short*)wsp; wsp += (size_t)BD * ND * DA * 2;
  unsigned short* vT  = (unsigned short*)wsp; wsp += (size_t)BD * CD * ND * 2;
  unsigned short* xTh = (unsigned short*)wsp; wsp += (size_t)BD * ND * CD * 2;  // aliased as y
  unsigned short* xTl = (unsigned short*)wsp; wsp += (size_t)BD * ND * CD * 2;
  unsigned short* Wch = (unsigned short*)wsp; wsp += (size_t)384 * 256 * 2;
  unsigned short* Wcl = (unsigned short*)wsp; wsp += (size_t)384 * 256 * 2;
  unsigned short* Wph = (unsigned short*)wsp; wsp += (size_t)256 * 256 * 2;
  unsigned short* Wpl = (unsigned short*)wsp; wsp += (size_t)256 * 256 * 2;
  float* Drec = (float*)wsp; wsp += (size_t)BD * ND * 4;
  float* Dp   = (float*)wsp; wsp += (size_t)2 * BD * ND * 4;
  unsigned short* y = xTh;  // xTh consumed+overwritten by k_attn epilogue

  dim3 blk(256), blk5(512);
  k_prep<<<dim3(ND / 64, CD / 64, BD), blk, 0, stream>>>(x, xTh, xTl);
  k_prepW<<<dim3(160), blk, 0, stream>>>(Wq, Wk, Wv, Wp, Wch, Wcl, Wph, Wpl);
  k_proj<<<dim3(ND / 128, BD), blk5, 0, stream>>>(xTh, xTl, Wch, Wcl, qhp, khp,
                                                  klp, vT);
  k_colsum<<<dim3(512), blk5, 0, stream>>>(qhp, khp, klp, Dp);
  k_rcp<<<dim3(32), blk, 0, stream>>>(Dp, Drec);
  k_attn<<<dim3(256), blk5, 0, stream>>>(qhp, khp, klp, vT, Drec, y, xTl);
  k_final<<<dim3(2048), blk, 0, stream>>>(y, Wph, x, gamma, beta, mean, var, out);
}

// Round 9
// 437.076 us; speedup vs baseline: 1.3553x; 1.1672x over previous
//
#include <hip/hip_runtime.h>
#include <math.h>

#define BD 8
#define CD 256
#define ND 4096
#define DA 64

typedef __attribute__((ext_vector_type(8))) short short8v;
typedef __attribute__((ext_vector_type(4))) float float4v;

static __device__ __forceinline__ float4v mfma16(short8v a, short8v b, float4v c) {
  return __builtin_amdgcn_mfma_f32_16x16x32_bf16(a, b, c, 0, 0, 0);
}
static __device__ __forceinline__ unsigned short f2bf(float f) {
  union { float f; unsigned int u; } v; v.f = f;
  return (unsigned short)((v.u + 0x7fffu + ((v.u >> 16) & 1u)) >> 16);
}
static __device__ __forceinline__ float bf2f(unsigned short h) {
  union { unsigned int u; float f; } v; v.u = (unsigned int)h << 16;
  return v.f;
}
// XOR-swizzled LDS offset (ushort units) for rows of 64 bf16 (8 x 16B chunks).
static __device__ __forceinline__ int sw(int row, int c8) {
  return row * 64 + (((c8) ^ (row & 7)) << 3);
}
typedef const __attribute__((address_space(1))) unsigned int g_u32;
typedef __attribute__((address_space(3))) unsigned int l_u32;
static __device__ __forceinline__ void gld16(const void* g, void* l) {
  __builtin_amdgcn_global_load_lds((g_u32*)g, (l_u32*)l, 16, 0, 0);
}

// ---------------------------------------------------------------------------
// k_prep: x [b][c][n] fp32 -> xTh/xTl [b][n][256] split bf16 (transposed).
// ---------------------------------------------------------------------------
__global__ __launch_bounds__(256) void k_prep(const float* __restrict__ x,
                                              unsigned short* __restrict__ xTh,
                                              unsigned short* __restrict__ xTl) {
  const int n0 = blockIdx.x * 64, c0 = blockIdx.y * 64, b = blockIdx.z;
  __shared__ float Xs[64][68];
  const int tid = threadIdx.x;
  const int r0 = tid >> 4, col4 = (tid & 15) * 4;
#pragma unroll
  for (int j = 0; j < 4; ++j) {
    int r = r0 + j * 16;
    *(float4*)&Xs[r][col4] =
        *(const float4*)&x[((size_t)(b * CD + c0 + r)) * ND + n0 + col4];
  }
  __syncthreads();
  const int n = tid >> 2, cg = (tid & 3) * 16;
  unsigned short h[16], l[16];
#pragma unroll
  for (int j = 0; j < 16; ++j) {
    float v = Xs[cg + j][n];
    h[j] = f2bf(v);
    l[j] = f2bf(v - bf2f(h[j]));
  }
  size_t o = ((size_t)b * ND + n0 + n) * CD + c0 + cg;
#pragma unroll
  for (int j = 0; j < 4; ++j) {
    *(ushort4*)&xTh[o + j * 4] = *(ushort4*)&h[j * 4];
    *(ushort4*)&xTl[o + j * 4] = *(ushort4*)&l[j * 4];
  }
}

// ---------------------------------------------------------------------------
// k_prepW: split weights fp32 -> bf16 hi/lo. Wch/Wcl = [Wq;Wk;Wv] rows 0..383.
// ---------------------------------------------------------------------------
__global__ void k_prepW(const float* __restrict__ Wq, const float* __restrict__ Wk,
                        const float* __restrict__ Wv, const float* __restrict__ Wp,
                        unsigned short* Wch, unsigned short* Wcl,
                        unsigned short* Wph, unsigned short* Wpl) {
  int i = blockIdx.x * 256 + threadIdx.x;  // 640 rows x 64 float4
  int row = i >> 6, c4 = (i & 63) * 4;
  const float* src; unsigned short *dh, *dl; int r, drow;
  if (row < 64)       { src = Wq; r = row;       dh = Wch; dl = Wcl; drow = row; }
  else if (row < 128) { src = Wk; r = row - 64;  dh = Wch; dl = Wcl; drow = row; }
  else if (row < 384) { src = Wv; r = row - 128; dh = Wch; dl = Wcl; drow = row; }
  else                { src = Wp; r = row - 384; dh = Wph; dl = Wpl; drow = row - 384; }
  float4 f = *(const float4*)&src[(size_t)r * 256 + c4];
  ushort4 hh, ll;
  hh.x = f2bf(f.x); hh.y = f2bf(f.y); hh.z = f2bf(f.z); hh.w = f2bf(f.w);
  ll.x = f2bf(f.x - bf2f(hh.x)); ll.y = f2bf(f.y - bf2f(hh.y));
  ll.z = f2bf(f.z - bf2f(hh.z)); ll.w = f2bf(f.w - bf2f(hh.w));
  *(ushort4*)&dh[(size_t)drow * 256 + c4] = hh;
  *(ushort4*)&dl[(size_t)drow * 256 + c4] = ll;
}

// ---------------------------------------------------------------------------
// k_proj: MERGED q/k/v projection (reads xT once, LDS k-slices, 3-product).
// grid (ND/128, B), 512 thr. q: hi only; k: hi+lo; v: transposed bf16.
// ---------------------------------------------------------------------------
__global__ __launch_bounds__(512) void k_proj(
    const unsigned short* __restrict__ xTh, const unsigned short* __restrict__ xTl,
    const unsigned short* __restrict__ Wch, const unsigned short* __restrict__ Wcl,
    unsigned short* __restrict__ qh, unsigned short* __restrict__ kh,
    unsigned short* __restrict__ kl, unsigned short* __restrict__ vT) {
  const int n0 = blockIdx.x * 128, b = blockIdx.y;
  const int tid = threadIdx.x, w = tid >> 6, lane = tid & 63, lq = lane & 15,
            quad = lane >> 4;
  __shared__ __align__(16) unsigned short xs[2][2][128][40];
  float4v O[24];
#pragma unroll
  for (int t = 0; t < 24; ++t) O[t] = (float4v){0.f, 0.f, 0.f, 0.f};

  const int srow = tid >> 2, sc4 = tid & 3;
  uint4 rh, rl;
  auto load_slice = [&](int ks) {
    size_t a = ((size_t)b * ND + n0 + srow) * CD + ks * 32 + sc4 * 8;
    rh = *(const uint4*)(xTh + a);
    rl = *(const uint4*)(xTl + a);
  };
  auto write_slice = [&](int buf) {
    *(uint4*)&xs[buf][0][srow][sc4 * 8] = rh;
    *(uint4*)&xs[buf][1][srow][sc4 * 8] = rl;
  };
  load_slice(0); write_slice(0);
#pragma unroll 1
  for (int ks = 0; ks < 8; ++ks) {
    __syncthreads();
    if (ks < 7) load_slice(ks + 1);
    short8v bxh = *(const short8v*)&xs[ks & 1][0][w * 16 + lq][quad * 8];
    short8v bxl = *(const short8v*)&xs[ks & 1][1][w * 16 + lq][quad * 8];
#pragma unroll
    for (int t = 0; t < 24; ++t) {
      size_t a = (size_t)(t * 16 + lq) * CD + ks * 32 + quad * 8;
      short8v awh = *(const short8v*)(Wch + a);
      short8v awl = *(const short8v*)(Wcl + a);
      O[t] = mfma16(awh, bxh, O[t]);
      O[t] = mfma16(awl, bxh, O[t]);
      O[t] = mfma16(awh, bxl, O[t]);
    }
    if (ks < 7) write_slice((ks + 1) & 1);
  }
  const int n = n0 + w * 16 + lq;
#pragma unroll
  for (int t = 0; t < 24; ++t) {
    if (t < 4) {
      ushort4 hh;
      hh.x = f2bf(O[t][0]); hh.y = f2bf(O[t][1]);
      hh.z = f2bf(O[t][2]); hh.w = f2bf(O[t][3]);
      *(ushort4*)&qh[((size_t)b * ND + n) * DA + t * 16 + quad * 4] = hh;
    } else if (t < 8) {
      ushort4 hh, ll;
      hh.x = f2bf(O[t][0]); hh.y = f2bf(O[t][1]);
      hh.z = f2bf(O[t][2]); hh.w = f2bf(O[t][3]);
      ll.x = f2bf(O[t][0] - bf2f(hh.x)); ll.y = f2bf(O[t][1] - bf2f(hh.y));
      ll.z = f2bf(O[t][2] - bf2f(hh.z)); ll.w = f2bf(O[t][3] - bf2f(hh.w));
      size_t o = ((size_t)b * ND + n) * DA + (t - 4) * 16 + quad * 4;
      *(ushort4*)&kh[o] = hh;
      *(ushort4*)&kl[o] = ll;
    } else {
#pragma unroll
      for (int r = 0; r < 4; ++r) {
        int c = (t - 8) * 16 + quad * 4 + r;
        vT[((size_t)b * CD + c) * ND + n] = f2bf(O[t][r]);
      }
    }
  }
}

// ---------------------------------------------------------------------------
// k_colsum v2: column sums of exp(e). DEPTH-2 PIPELINE: body(i) computes
// MFMA(i) while the exp/add chain of iter i-1 runs (accP ready at body
// start -> VALU no longer serializes behind this body's MFMAs). Staging,
// barriers, numerics and cs accumulation order identical to R5.
// ---------------------------------------------------------------------------
__global__ __launch_bounds__(512, 4) void k_colsum(
    const unsigned short* __restrict__ qh, const unsigned short* __restrict__ khp,
    const unsigned short* __restrict__ klp, float* __restrict__ Dp) {
  const int bid = blockIdx.x, b = bid & 7, half = (bid >> 3) & 1,
            m0 = (bid >> 4) * 128;
  const int nbase = half * 2048;
  const int tid = threadIdx.x, w = tid >> 6, lane = tid & 63, lq = lane & 15,
            quad = lane >> 4;
  const int mq = w & 3, nh = w >> 2;
  __shared__ __align__(16) unsigned short qbuf[3][4096];  // 64n x 64d swizzled
  __shared__ float Cb[128];
  short8v bkh[2][2], bkl[2][2];
#pragma unroll
  for (int sub = 0; sub < 2; ++sub)
#pragma unroll
    for (int k = 0; k < 2; ++k) {
      size_t a = ((size_t)b * ND + m0 + mq * 32 + sub * 16 + lq) * DA + k * 32 + quad * 8;
      bkh[sub][k] = *(const short8v*)(khp + a);
      bkl[sub][k] = *(const short8v*)(klp + a);
    }
  // async staging: 512 chunks/tile, 1 per thread; swizzle baked into source
  const int srow = w * 8 + (lane >> 3), sck = lane & 7;
  auto stageQ = [&](int it, int qn) {
    const unsigned short* src = qh + ((size_t)b * ND + nbase + it * 64 + srow) * DA +
                                ((sck ^ (srow & 7)) << 3);
    gld16(src, &qbuf[qn][0] + (size_t)w * 512);
  };
  stageQ(0, 0);
  stageQ(1, 1);
  // stage(0) retired for everyone; stage(1) still in flight
  asm volatile("s_waitcnt vmcnt(1)\n\ts_barrier" ::: "memory");
  float cs0 = 0.f, cs1 = 0.f;
  float4v accP[2][2];
  int rc = 0, sc = 2;
#pragma unroll 1
  for (int i = 0; i < 32; ++i) {
    if (i < 30) { stageQ(i + 2, sc); sc = (sc + 1 == 3) ? 0 : sc + 1; }
    // ---- MFMA(i) from qbuf[rc] (guaranteed ready by previous barrier) ----
    float4v accN[2][2];
#pragma unroll
    for (int s = 0; s < 2; ++s) {
      short8v ah[2];
#pragma unroll
      for (int k = 0; k < 2; ++k)
        ah[k] = *(const short8v*)&qbuf[rc][sw(nh * 32 + s * 16 + lq, k * 4 + quad)];
#pragma unroll
      for (int sub = 0; sub < 2; ++sub) {
        float4v acc = {0.f, 0.f, 0.f, 0.f};
#pragma unroll
        for (int k = 0; k < 2; ++k) {
          acc = mfma16(ah[k], bkh[sub][k], acc);
          acc = mfma16(ah[k], bkl[sub][k], acc);
        }
        accN[s][sub] = acc;
      }
    }
    // ---- exp(i-1) from accP: independent of this body's MFMAs ----
    if (i > 0) {
#pragma unroll
      for (int s = 0; s < 2; ++s)
#pragma unroll
        for (int sub = 0; sub < 2; ++sub) {
          float e0 = __expf(accP[s][sub][0]) + __expf(accP[s][sub][1]) +
                     __expf(accP[s][sub][2]) + __expf(accP[s][sub][3]);
          if (sub == 0) cs0 += e0; else cs1 += e0;
        }
    }
#pragma unroll
    for (int s = 0; s < 2; ++s)
#pragma unroll
      for (int sub = 0; sub < 2; ++sub) accP[s][sub] = accN[s][sub];
    rc = (rc + 1 == 3) ? 0 : rc + 1;
    // counted barrier: stage(i+1) (older) retired, stage(i+2) stays in flight
    if (i < 30)
      asm volatile("s_waitcnt vmcnt(1) lgkmcnt(0)\n\ts_barrier" ::: "memory");
    else
      asm volatile("s_waitcnt vmcnt(0) lgkmcnt(0)\n\ts_barrier" ::: "memory");
  }
  // epilogue: exp(31)
#pragma unroll
  for (int s = 0; s < 2; ++s)
#pragma unroll
    for (int sub = 0; sub < 2; ++sub) {
      float e0 = __expf(accP[s][sub][0]) + __expf(accP[s][sub][1]) +
                 __expf(accP[s][sub][2]) + __expf(accP[s][sub][3]);
      if (sub == 0) cs0 += e0; else cs1 += e0;
    }
  cs0 += __shfl_down(cs0, 16); cs0 += __shfl_down(cs0, 32);
  cs1 += __shfl_down(cs1, 16); cs1 += __shfl_down(cs1, 32);
  if (nh == 0 && lane < 16) {
    Cb[mq * 32 + lane] = cs0;
    Cb[mq * 32 + 16 + lane] = cs1;
  }
  __syncthreads();
  if (nh == 1 && lane < 16) {
    float t0 = Cb[mq * 32 + lane] + cs0;
    float t1 = Cb[mq * 32 + 16 + lane] + cs1;
    size_t o = (size_t)half * (BD * ND) + (size_t)b * ND + m0 + mq * 32 + lane;
    Dp[o] = t0;
    Dp[o + 16] = t1;
  }
}

// combine halves: Drec = 1/(Dp0+Dp1). grid 32 x 256.
__global__ void k_rcp(const float* __restrict__ Dp, float* __restrict__ Drec) {
  int i = blockIdx.x * 256 + threadIdx.x;
  float4 a = *(const float4*)&Dp[(size_t)i * 4];
  float4 c = *(const float4*)&Dp[(size_t)(BD * ND) + (size_t)i * 4];
  float4 r;
  r.x = 1.f / (a.x + c.x); r.y = 1.f / (a.y + c.y);
  r.z = 1.f / (a.z + c.z); r.w = 1.f / (a.w + c.w);
  *(float4*)&Drec[(size_t)i * 4] = r;
}

// ---------------------------------------------------------------------------
// k_attn v9: R5 structure (mt4 x nh2 waves, triple vbuf, dbuf Pb, counted
// vmcnt(4) barrier — 176.5us verified) + DEPTH-2 EXP PIPELINE:
//   body(i) = [ PV(i-1)  (Pb+vbuf LDS reads -> MFMA)
//             ∥ expPack(i) from accP (e-MFMA result computed LAST body ->
//               the VALU chain is ready at body start, no longer serialized
//               behind this body's matrix ops)
//             ∥ kload/dload/stage(i+1)
//             ; eMFMA(i+1) -> accP  (new kc, at body end)
//             ; barrier vmcnt(4) ]
// kn eliminated (kc reloaded in place, R6-proven WAR-safe: loads issue after
// the MFMAs that read kc). Numerics/accumulation order identical to R5.
// ---------------------------------------------------------------------------
__global__ __launch_bounds__(512, 2) void k_attn(
    const unsigned short* __restrict__ qh, const unsigned short* __restrict__ khp,
    const unsigned short* __restrict__ klp, const unsigned short* __restrict__ vT,
    const float* __restrict__ Drec, unsigned short* xhy,
    const unsigned short* __restrict__ xTl) {
  const int bid = blockIdx.x, b = bid & 7, n0 = (bid >> 3) * 128;
  const int tid = threadIdx.x, w = tid >> 6, lane = tid & 63, lq = lane & 15,
            quad = lane >> 4;
  const int nh = w & 1, mt = w >> 1;  // 2 n-halves x 4 m/c-quarters
  __shared__ __align__(16) unsigned short vbuf[3][16384];  // 256c x 64m swizzled
  __shared__ __align__(16) unsigned short Pb[2][8192];     // 128n x 64m swizzled
  __shared__ float Sb4[4][128];

  // q B-frags (hi only), resident: wave's 64-n half
  short8v aq[4][2];
#pragma unroll
  for (int s = 0; s < 4; ++s)
#pragma unroll
    for (int k = 0; k < 2; ++k)
      aq[s][k] = *(const short8v*)(qh + ((size_t)b * ND + n0 + nh * 64 + s * 16 + lq) * DA +
                                   k * 32 + quad * 8);
  float4v O[4][4];  // [ct][s]
#pragma unroll
  for (int ct = 0; ct < 4; ++ct)
#pragma unroll
    for (int s = 0; s < 4; ++s) O[ct][s] = (float4v){0.f, 0.f, 0.f, 0.f};
  float rs[4] = {0.f, 0.f, 0.f, 0.f};

  // async vT staging: 2048 chunks, 4/thread, swizzle baked into source
  auto stageV = [&](int mtile, int vn) {
    unsigned short* base = &vbuf[vn][0];
#pragma unroll
    for (int j = 0; j < 4; ++j) {
      int cidx = tid + j * 512;
      int row = cidx >> 3, ckpos = cidx & 7;
      const unsigned short* src =
          vT + ((size_t)b * CD + row) * ND + mtile * 64 + ((ckpos ^ (row & 7)) << 3);
      gld16(src, base + (size_t)(w * 64 + j * 512) * 8);
    }
  };
  short8v kc[4];  // [k*2 + (h|l)]; wave's 16 K-rows = m-quarter mt (in-place)
  auto kload = [&](int mtile) {
#pragma unroll
    for (int k = 0; k < 2; ++k) {
      size_t a = ((size_t)b * ND + mtile * 64 + mt * 16 + lq) * DA + k * 32 + quad * 8;
      kc[k * 2 + 0] = *(const short8v*)(khp + a);
      kc[k * 2 + 1] = *(const short8v*)(klp + a);
    }
  };
  auto doPV = [&](const unsigned short* Pc, const unsigned short* vc) {
#pragma unroll
    for (int ks = 0; ks < 2; ++ks) {
      short8v ap[4];
#pragma unroll
      for (int s = 0; s < 4; ++s)
        ap[s] = *(const short8v*)&Pc[sw(nh * 64 + s * 16 + lq, ks * 4 + quad)];
#pragma unroll
      for (int ct = 0; ct < 4; ++ct) {
        const int trow = (mt * 4 + ct) * 16 + lq;
        short8v bv = *(const short8v*)&vc[sw(trow, ks * 4 + quad)];
#pragma unroll
        for (int s = 0; s < 4; ++s) O[ct][s] = mfma16(bv, ap[s], O[ct][s]);
      }
    }
  };
  auto eMFMA = [&](float4v* dst) {
#pragma unroll
    for (int s = 0; s < 4; ++s) {
      float4v acc = {0.f, 0.f, 0.f, 0.f};
#pragma unroll
      for (int k = 0; k < 2; ++k) {
        acc = mfma16(kc[k * 2 + 0], aq[s][k], acc);
        acc = mfma16(kc[k * 2 + 1], aq[s][k], acc);
      }
      dst[s] = acc;
    }
  };

  float4 drc4, drn4;
  stageV(0, 0);
  kload(0);
  drc4 = *(const float4*)&Drec[(size_t)b * ND + mt * 16 + quad * 4];
  // prologue: e-MFMA(0) (compiler waits on kc loads)
  float4v accP[4];
  eMFMA(accP);

  int vs = 1, vp = 0;
#pragma unroll 1
  for (int i = 0; i < 64; ++i) {
    if (i > 0) {
      doPV(&Pb[(i - 1) & 1][0], &vbuf[vp][0]);
      vp = (vp + 1 == 3) ? 0 : vp + 1;
    }
    if (i < 63) {
      kload(i + 1);  // in-place: kc's last read was eMFMA at end of prev body
      drn4 = *(const float4*)&Drec[(size_t)b * ND + (i + 1) * 64 + mt * 16 + quad * 4];
      stageV(i + 1, vs);
      vs = (vs + 1 == 3) ? 0 : vs + 1;
    }
    // ---- expPack(i): accP ready at body start -> overlaps PV's MFMAs ----
    unsigned short* Pcur = &Pb[i & 1][0];
#pragma unroll
    for (int s = 0; s < 4; ++s) {
      float p0 = __expf(accP[s][0]) * drc4.x;
      float p1 = __expf(accP[s][1]) * drc4.y;
      float p2 = __expf(accP[s][2]) * drc4.z;
      float p3 = __expf(accP[s][3]) * drc4.w;
      rs[s] += (p0 + p1) + (p2 + p3);
      unsigned int w0 =
          (__float_as_uint(p0) >> 16) | (__float_as_uint(p1) & 0xffff0000u);
      unsigned int w1 =
          (__float_as_uint(p2) >> 16) | (__float_as_uint(p3) & 0xffff0000u);
      const int nl = nh * 64 + s * 16 + lq;
      const int c8 = mt * 2 + (quad >> 1);
      uint2 wv; wv.x = w0; wv.y = w1;
      *(uint2*)&Pcur[nl * 64 + ((c8 ^ (nl & 7)) << 3) + ((quad & 1) << 2)] = wv;
    }
    if (i < 63) {
      eMFMA(accP);  // for iter i+1, from the kc loaded this body
      drc4 = drn4;
    }
    // counted barrier: keep THIS body's 4 stage chunks in flight (consumed
    // at body(i+2)); kc/drn consumed above -> retired; stage(i) older ->
    // retired. Exactly 4 outstanding at the barrier.
    if (i < 63)
      asm volatile("s_waitcnt vmcnt(4) lgkmcnt(0)\n\ts_barrier" ::: "memory");
    else
      asm volatile("s_waitcnt vmcnt(0) lgkmcnt(0)\n\ts_barrier" ::: "memory");
  }
  doPV(&Pb[1][0], &vbuf[vp][0]);  // PV(63); 63&1 == 1, 63%3 == 0

  // ---- S reduction: butterfly over quad, then 4-way mt combine in LDS ----
#pragma unroll
  for (int s = 0; s < 4; ++s) {
    rs[s] += __shfl_xor(rs[s], 16);
    rs[s] += __shfl_xor(rs[s], 32);
  }
  if (lane < 16) {
#pragma unroll
    for (int s = 0; s < 4; ++s) Sb4[mt][nh * 64 + s * 16 + lane] = rs[s];
  }
  __syncthreads();
  float rsc[4];
#pragma unroll
  for (int s = 0; s < 4; ++s) {
    const int nloc = nh * 64 + s * 16 + lq;
    rsc[s] = 1.0f / (1e-9f + Sb4[0][nloc] + Sb4[1][nloc] + Sb4[2][nloc] + Sb4[3][nloc]);
  }
  // ---- y = x - O/S, in place over xTh (lane: 4 consecutive c, fixed n) ----
#pragma unroll
  for (int ct = 0; ct < 4; ++ct) {
    const int cb = (mt * 4 + ct) * 16 + quad * 4;
#pragma unroll
    for (int s = 0; s < 4; ++s) {
      const int n = n0 + nh * 64 + s * 16 + lq;
      const size_t off = ((size_t)b * ND + n) * CD + cb;
      ushort4 h4 = *(const ushort4*)&xhy[off];
      ushort4 l4 = *(const ushort4*)&xTl[off];
      ushort4 o4;
      o4.x = f2bf(bf2f(h4.x) + bf2f(l4.x) - O[ct][s][0] * rsc[s]);
      o4.y = f2bf(bf2f(h4.y) + bf2f(l4.y) - O[ct][s][1] * rsc[s]);
      o4.z = f2bf(bf2f(h4.z) + bf2f(l4.z) - O[ct][s][2] * rsc[s]);
      o4.w = f2bf(bf2f(h4.w) + bf2f(l4.w) - O[ct][s][3] * rsc[s]);
      *(ushort4*)&xhy[off] = o4;
    }
  }
}

// ---------------------------------------------------------------------------
// k_final: h = Wp . y (bf16 MFMA); out = relu(BN(h)) + x.
// ---------------------------------------------------------------------------
__global__ __launch_bounds__(256) void k_final(const unsigned short* __restrict__ y,
                                               const unsigned short* __restrict__ Wpb,
                                               const float* __restrict__ x,
                                               const float* __restrict__ gamma,
                                               const float* __restrict__ beta,
                                               const float* __restrict__ mean,
                                               const float* __restrict__ var,
                                               float* __restrict__ out) {
  const int bid = blockIdx.x;
  const int b = bid & 7;
  const int rem = bid >> 3;
  const int n0 = (rem & 63) * 64;
  const int d0 = (rem >> 6) * 64;
  const int tid = threadIdx.x;
  const int wave = tid >> 6, lane = tid & 63, lq = lane & 15, quad = lane >> 4;
  const int dw = d0 + wave * 16;
  float4v O[4];
#pragma unroll
  for (int s = 0; s < 4; ++s) O[s] = (float4v){0.f, 0.f, 0.f, 0.f};
#pragma unroll
  for (int chh = 0; chh < 8; ++chh) {
    const size_t ab = (size_t)(dw + lq) * CD + chh * 32 + quad * 8;
    short8v a0 = *(const short8v*)(Wpb + ab);
#pragma unroll
    for (int s = 0; s < 4; ++s) {
      const size_t bb = ((size_t)b * ND + n0 + s * 16 + lq) * CD + chh * 32 + quad * 8;
      short8v bv = *(const short8v*)(y + bb);
      O[s] = mfma16(a0, bv, O[s]);
    }
  }
#pragma unroll
  for (int r = 0; r < 4; ++r) {
    const int d = dw + quad * 4 + r;
    const float inv  = gamma[d] / sqrtf(var[d] + 1e-5f);
    const float bias = beta[d] - mean[d] * inv;
#pragma unroll
    for (int s = 0; s < 4; ++s) {
      const int n = n0 + s * 16 + lq;
      const size_t oi = ((size_t)b * CD + d) * ND + n;
      out[oi] = fmaxf(O[s][r] * inv + bias, 0.f) + x[oi];
    }
  }
}

extern "C" void kernel_launch(void* const* d_in, const int* in_sizes, int n_in,
                              void* d_out, int out_size, void* d_ws, size_t ws_size,
                              hipStream_t stream) {
  const float* x     = (const float*)d_in[0];
  const float* Wq    = (const float*)d_in[1];
  const float* Wk    = (const float*)d_in[2];
  const float* Wv    = (const float*)d_in[3];
  const float* Wp    = (const float*)d_in[4];
  const float* gamma = (const float*)d_in[5];
  const float* beta  = (const float*)d_in[6];
  const float* mean  = (const float*)d_in[7];
  const float* var   = (const float*)d_in[8];
  float* out = (float*)d_out;

  char* wsp = (char*)d_ws;
  unsigned short* qhp = (unsigned short*)wsp; wsp += (size_t)BD * ND * DA * 2;
  unsigned short* khp = (unsigned short*)wsp; wsp += (size_t)BD * ND * DA * 2;
  unsigned short* klp = (unsigned short*)wsp; wsp += (size_t)BD * ND * DA * 2;
  unsigned short* vT  = (unsigned short*)wsp; wsp += (size_t)BD * CD * ND * 2;
  unsigned short* xTh = (unsigned short*)wsp; wsp += (size_t)BD * ND * CD * 2;  // aliased as y
  unsigned short* xTl = (unsigned short*)wsp; wsp += (size_t)BD * ND * CD * 2;
  unsigned short* Wch = (unsigned short*)wsp; wsp += (size_t)384 * 256 * 2;
  unsigned short* Wcl = (unsigned short*)wsp; wsp += (size_t)384 * 256 * 2;
  unsigned short* Wph = (unsigned short*)wsp; wsp += (size_t)256 * 256 * 2;
  unsigned short* Wpl = (unsigned short*)wsp; wsp += (size_t)256 * 256 * 2;
  float* Drec = (float*)wsp; wsp += (size_t)BD * ND * 4;
  float* Dp   = (float*)wsp; wsp += (size_t)2 * BD * ND * 4;
  unsigned short* y = xTh;  // xTh consumed+overwritten by k_attn epilogue

  dim3 blk(256), blk5(512);
  k_prep<<<dim3(ND / 64, CD / 64, BD), blk, 0, stream>>>(x, xTh, xTl);
  k_prepW<<<dim3(160), blk, 0, stream>>>(Wq, Wk, Wv, Wp, Wch, Wcl, Wph, Wpl);
  k_proj<<<dim3(ND / 128, BD), blk5, 0, stream>>>(xTh, xTl, Wch, Wcl, qhp, khp,
                                                  klp, vT);
  k_colsum<<<dim3(512), blk5, 0, stream>>>(qhp, khp, klp, Dp);
  k_rcp<<<dim3(32), blk, 0, stream>>>(Dp, Drec);
  k_attn<<<dim3(256), blk5, 0, stream>>>(qhp, khp, klp, vT, Drec, y, xTl);
  k_final<<<dim3(2048), blk, 0, stream>>>(y, Wph, x, gamma, beta, mean, var, out);
}